// Round 8
// baseline (2612.294 us; speedup 1.0000x reference)
//
#include <hip/hip_runtime.h>

typedef unsigned short u16;

#define NROW 8192

__device__ __forceinline__ float bf2f(u16 h) {
  unsigned u = ((unsigned)h) << 16;
  return __builtin_bit_cast(float, u);
}
// mode-aware load: f32 ? fp32 storage : bf16 storage (upcast)
__device__ __forceinline__ float ldf(const void* p, size_t i, int f32) {
  return f32 ? ((const float*)p)[i] : bf2f(((const u16*)p)[i]);
}
// order-preserving float->uint key for atomicMax
__device__ __forceinline__ unsigned fkey(float f) {
  unsigned b = __builtin_bit_cast(unsigned, f);
  return (b & 0x80000000u) ? ~b : (b | 0x80000000u);
}
__device__ __forceinline__ float fkeydec(unsigned k) {
  unsigned b = (k & 0x80000000u) ? (k & 0x7FFFFFFFu) : ~k;
  return __builtin_bit_cast(float, b);
}

// ---- storage-dtype detection on x (N(0,1)).
__global__ void detect3(const u16* __restrict__ xr, unsigned* __restrict__ mode) {
  __shared__ int zc, bg;
  int t = threadIdx.x;   // 256
  if (t == 0) { zc = 0; bg = 0; }
  __syncthreads();
  int zeros_even = 0; int big = 0;
  for (int i = t; i < 4096; i += 256) {
    u16 v = xr[i];
    if (!(i & 1) && v == 0) zeros_even++;
    if (fabsf(bf2f(v)) > 1e6f) big = 1;
  }
  atomicAdd(&zc, zeros_even);
  if (big) atomicOr(&bg, 1);
  __syncthreads();
  if (t == 0) *mode = (zc > 512 || bg) ? 1u : 0u;   // 1 = fp32 storage
}

// ---- adj storage detection (u32 pair pattern 0x00003F80 unique to bf16).
__global__ void detect_adj(const unsigned* __restrict__ a, unsigned* __restrict__ amode) {
  __shared__ int clo;
  int t = threadIdx.x;   // 256
  if (t == 0) clo = 0;
  __syncthreads();
  int c = 0;
  for (int i = t; i < 4096; i += 256)
    if (a[i] == 0x00003F80u) c++;
  atomicAdd(&clo, c);
  __syncthreads();
  if (t == 0) *amode = (clo > 32) ? 1u : 0u;   // 1 = bf16 storage
}

// 4 adjacency bits at element offset base (base % 4 == 0).
__device__ __forceinline__ void mask4(const void* adj, size_t base, int amode, int* aa) {
  if (amode == 0) {   // int32 or fp32 storage: one u32 per element, !=0 test
    int4 av = *(const int4*)((const int*)adj + base);
    aa[0] = av.x != 0; aa[1] = av.y != 0; aa[2] = av.z != 0; aa[3] = av.w != 0;
  } else {            // bf16 storage: one u16 per element
    ushort4 av = *(const ushort4*)((const u16*)adj + base);
    aa[0] = av.x != 0; aa[1] = av.y != 0; aa[2] = av.z != 0; aa[3] = av.w != 0;
  }
}

// C[M x N] fp32 = A[M x K] @ B[K x N]; A/B raw (mode-aware) or fp32 ws buffers.
__global__ __launch_bounds__(256) void gemm_f32(const void* __restrict__ A,
    const void* __restrict__ B, float* __restrict__ C, int K, int N,
    const unsigned* __restrict__ modep, int araw, int braw) {
  int f32a = araw ? (int)*modep : 1;
  int f32b = braw ? (int)*modep : 1;
  __shared__ float sA[16][68];
  __shared__ float sB[16][68];
  int tid = threadIdx.x;
  int rb = blockIdx.y, cb = blockIdx.x;
  int tx = tid & 15, ty = tid >> 4;
  float acc[4][4] = {};
  for (int kt = 0; kt < K; kt += 16) {
    __syncthreads();
#pragma unroll
    for (int it = 0; it < 4; ++it) {
      int idx = tid + it * 256;          // 0..1023
      int m = idx & 63, kk = idx >> 6;
      sA[kk][m] = ldf(A, (size_t)(rb * 64 + m) * K + kt + kk, f32a);
      sB[kk][m] = ldf(B, (size_t)(kt + kk) * N + cb * 64 + m, f32b);
    }
    __syncthreads();
#pragma unroll
    for (int k = 0; k < 16; ++k) {
      float4 av = *(const float4*)&sA[k][ty * 4];
      float4 bv = *(const float4*)&sB[k][tx * 4];
      float aa[4] = {av.x, av.y, av.z, av.w};
      float bb[4] = {bv.x, bv.y, bv.z, bv.w};
#pragma unroll
      for (int r = 0; r < 4; ++r)
#pragma unroll
        for (int c = 0; c < 4; ++c) acc[r][c] += aa[r] * bb[c];
    }
  }
#pragma unroll
  for (int r = 0; r < 4; ++r)
#pragma unroll
    for (int c = 0; c < 4; ++c)
      C[(size_t)(rb * 64 + ty * 4 + r) * N + cb * 64 + tx * 4 + c] = acc[r][c];
}

// s_i = Wh_i . a[:F], d_i = Wh_i . a[F:] (Wh fp32, a raw), + global Dmax.
__global__ __launch_bounds__(256) void sd_f32(const float* __restrict__ Wh,
    const void* __restrict__ a2, float* __restrict__ s, float* __restrict__ d,
    unsigned* __restrict__ cell, int F, const unsigned* __restrict__ modep) {
  int f32 = (int)*modep;
  int row = blockIdx.x * 4 + (threadIdx.x >> 6);
  int l = threadIdx.x & 63;
  float ss = 0.f, dd = 0.f;
  for (int k = l; k < F; k += 64) {
    float wv = Wh[(size_t)row * F + k];
    ss += wv * ldf(a2, k, f32);
    dd += wv * ldf(a2, F + k, f32);
  }
#pragma unroll
  for (int off = 32; off > 0; off >>= 1) {
    ss += __shfl_down(ss, off, 64);
    dd += __shfl_down(dd, off, 64);
  }
  if (l == 0) {
    s[row] = ss; d[row] = dd;
    atomicMax(cell, fkey(dd));
  }
}

// Full-fp32 flash GAT layer (see round-5/6 notes).
template <int FDIM, int R, int RPG, int JS, bool ELU>
__global__ __launch_bounds__(256) void flash_f32(const float* __restrict__ Wh,
    const float* __restrict__ s, const float* __restrict__ d,
    const unsigned* __restrict__ cell, const void* __restrict__ adj,
    const unsigned* __restrict__ amodep,
    float* __restrict__ outf, float* __restrict__ lps) {
  constexpr int PST = R + 4;            // Pt j-row stride (floats)
  constexpr int NFG = FDIM / 8;         // feature groups
  constexpr int NRG = 256 / NFG;        // row groups
  static_assert(NRG * RPG == R, "thread geometry");
  static_assert(RPG == 2 || RPG == 4, "RPG path");
  constexpr int JLEN = NROW / JS;
  __shared__ __align__(16) float wt[32 * FDIM];
  __shared__ __align__(16) float Pt[32 * PST];
  __shared__ float sd_[R], Ms_[R], lsum_[R], dd_[32];
  int tid = threadIdx.x;
  int amode = (int)*amodep;
  int rblk = blockIdx.x / JS;
  int js   = blockIdx.x - rblk * JS;
  int r0 = rblk * R;
  int jbase = js * JLEN;
  int fg = tid % NFG, rg = tid / NFG;
  float Dmax = fkeydec(*cell);
  for (int i = tid; i < R; i += 256) {
    float sv = s[r0 + i];
    sd_[i] = sv;
    float t = sv + Dmax;
    Ms_[i] = fmaxf(t, 0.2f * t);        // lrelu(s_i + Dmax) >= all e[i,:]
    lsum_[i] = 0.f;
  }
  float acc[RPG][8] = {};
  for (int j0 = jbase; j0 < jbase + JLEN; j0 += 32) {
    __syncthreads();                    // prior readers of wt/Pt/dd_ done
    if (tid < 32) dd_[tid] = d[j0 + tid];
    for (int u = tid; u < 32 * FDIM / 4; u += 256)
      *(float4*)&wt[u * 4] = *(const float4*)&Wh[(size_t)j0 * FDIM + u * 4];
    __syncthreads();                    // wt/dd_ ready
    for (int u = tid; u < R * 8; u += 256) {
      int r = u >> 3, jq = (u & 7) * 4;
      int aa[4];
      mask4(adj, (size_t)(r0 + r) * NROW + j0 + jq, amode, aa);
      float sv = sd_[r], Mr = Ms_[r];
      float psum = 0.f;
#pragma unroll
      for (int i2 = 0; i2 < 4; ++i2) {
        float t = sv + dd_[jq + i2];
        float e = fmaxf(t, 0.2f * t) - Mr;       // <= 0
        float p = aa[i2] ? __expf(e) : 0.f;
        psum += p;
        Pt[(jq + i2) * PST + r] = p;             // j-major
      }
      atomicAdd(&lsum_[r], psum);
    }
    __syncthreads();                    // Pt complete
#pragma unroll 4
    for (int j = 0; j < 32; ++j) {
      float4 w0 = *(const float4*)&wt[j * FDIM + fg * 8];
      float4 w1 = *(const float4*)&wt[j * FDIM + fg * 8 + 4];
      float wv[8] = {w0.x, w0.y, w0.z, w0.w, w1.x, w1.y, w1.z, w1.w};
      float pv[RPG];
      if constexpr (RPG == 4) {
        float4 p0 = *(const float4*)&Pt[j * PST + rg * 4];
        pv[0] = p0.x; pv[1] = p0.y; pv[2] = p0.z; pv[3] = p0.w;
      } else {   // RPG == 2
        float2 p0 = *(const float2*)&Pt[j * PST + rg * 2];
        pv[0] = p0.x; pv[1] = p0.y;
      }
#pragma unroll
      for (int rr = 0; rr < RPG; ++rr)
#pragma unroll
        for (int b = 0; b < 8; ++b) acc[rr][b] += pv[rr] * wv[b];
    }
  }
  __syncthreads();                      // last chunk's lsum adds done
  if (JS == 1) {
#pragma unroll
    for (int rr = 0; rr < RPG; ++rr) {
      int rl = rg * RPG + rr;
      float inv = 1.f / lsum_[rl];
#pragma unroll
      for (int b = 0; b < 8; ++b) {
        float x = acc[rr][b] * inv;
        if (ELU) x = (x > 0.f) ? x : (__expf(x) - 1.f);
        outf[(size_t)(r0 + rl) * FDIM + fg * 8 + b] = x;
      }
    }
  } else {
    float* op = outf + (size_t)js * NROW * FDIM;
#pragma unroll
    for (int rr = 0; rr < RPG; ++rr) {
      int rl = rg * RPG + rr;
#pragma unroll
      for (int b = 0; b < 8; ++b)
        op[(size_t)(r0 + rl) * FDIM + fg * 8 + b] = acc[rr][b];
    }
    for (int i = tid; i < R; i += 256)
      lps[(size_t)js * NROW + r0 + i] = lsum_[i];
  }
}

// combine 4 j-split partials: out = sum(parts)/sum(lsums); fp32 out (x2).
__global__ __launch_bounds__(256) void combine4(const float* __restrict__ parts,
    const float* __restrict__ lps, float* __restrict__ outf, float* __restrict__ outd) {
  int idx = blockIdx.x * 256 + threadIdx.x;   // 8192*64 total
  int row = idx >> 6;
  const size_t S = (size_t)NROW * 64;
  float v = parts[idx] + parts[S + idx] + parts[2 * S + idx] + parts[3 * S + idx];
  float l = lps[row] + lps[NROW + row] + lps[2 * NROW + row] + lps[3 * NROW + row];
  float x = v / l;
  outf[idx] = x;
  outd[idx] = x;            // fp32 output store (d_out region)
}

// logits = (mu + eps*exp(0.5*logvar)) @ Wc + bc (mu/lv fp32, rest raw). fp32 out.
__global__ __launch_bounds__(256) void logits_f32(const float* __restrict__ mu,
    const float* __restrict__ lv, const void* __restrict__ eps,
    const void* __restrict__ Wc, const void* __restrict__ bcv,
    float* __restrict__ outL, const unsigned* __restrict__ modep) {
  int f32 = (int)*modep;
  __shared__ float zs[64 * 64];
  __shared__ float wcs[64 * 16];
  int tid = threadIdx.x;
  for (int i = tid; i < 1024; i += 256) wcs[i] = ldf(Wc, i, f32);
  int rl = tid >> 2, cs = (tid & 3) * 16;
  int row = blockIdx.x * 64 + rl;
  size_t rb64 = (size_t)row * 64;
  for (int c = cs; c < cs + 16; ++c)
    zs[rl * 64 + c] = mu[rb64 + c] + ldf(eps, rb64 + c, f32) * __expf(0.5f * lv[rb64 + c]);
  __syncthreads();
  for (int it = tid; it < 1024; it += 256) {
    int r = it >> 4, oc = it & 15;
    float a = ldf(bcv, oc, f32);
    for (int c = 0; c < 64; ++c) a += zs[r * 64 + c] * wcs[c * 16 + oc];
    outL[(size_t)(blockIdx.x * 64 + r) * 16 + oc] = a;
  }
}

extern "C" void kernel_launch(void* const* d_in, const int* in_sizes, int n_in,
                              void* d_out, int out_size, void* d_ws, size_t ws_size,
                              hipStream_t stream) {
  (void)out_size; (void)ws_size;
  // ---- size-based input resolution (robust to permutation; ties in dict order)
  int ix = 0, iadj = 1, ieps = 2, iW1 = 3, ia1 = 4, iWmu = 5, iamu = 6,
      iWlv = 7, ialv = 8, iWc = 9, ibc = 10;
  {
    int fmu = -1, flv = -1, fam = -1, fal = -1;
    for (int i = 0; i < n_in; ++i) {
      switch (in_sizes[i]) {
        case 67108864: iadj = i; break;
        case 4194304:  ix   = i; break;
        case 524288:   ieps = i; break;
        case 131072:   iW1  = i; break;
        case 512:      ia1  = i; break;
        case 1024:     iWc  = i; break;
        case 16:       ibc  = i; break;
        case 16384:    if (fmu < 0) fmu = i; else flv = i; break;
        case 128:      if (fam < 0) fam = i; else fal = i; break;
        default: break;
      }
    }
    if (fmu >= 0 && flv >= 0) { iWmu = fmu; iWlv = flv; }
    if (fam >= 0 && fal >= 0) { iamu = fam; ialv = fal; }
  }
  const void* adj = d_in[iadj];
  char* ws = (char*)d_ws;
  const size_t KB = 1024, MB = 1024 * 1024;
  // ---- workspace (<= 24.5 MB) ----
  float* wh1   = (float*)(ws + 0);                 // 8MB  [gemm1 -> sd1/flash1]
  float* parts = (float*)(ws + 0);                 // 8MB  [overlays wh1; flash2 partials]
  float* h     = (float*)(ws + 8 * MB);            // 8MB
  float* whmu  = (float*)(ws + 16 * MB);           // 2MB
  float* whlv  = (float*)(ws + 18 * MB);           // 2MB
  float* muf   = (float*)(ws + 20 * MB);           // 2MB
  float* lvf   = (float*)(ws + 22 * MB);           // 2MB
  float* lps   = (float*)(ws + 24 * MB);           // 128KB (4*8192*4)
  float* s1    = (float*)(ws + 24 * MB + 128 * KB);
  float* d1    = (float*)(ws + 24 * MB + 160 * KB);
  float* smu   = (float*)(ws + 24 * MB + 192 * KB);
  float* dmu   = (float*)(ws + 24 * MB + 224 * KB);
  float* slv   = (float*)(ws + 24 * MB + 256 * KB);
  float* dlv   = (float*)(ws + 24 * MB + 288 * KB);
  unsigned* dmx   = (unsigned*)(ws + 24 * MB + 320 * KB);  // 4 cells
  unsigned* mode  = (unsigned*)(ws + 24 * MB + 321 * KB);
  unsigned* amode = (unsigned*)(ws + 24 * MB + 322 * KB);

  // fp32 output layout: [logits 8192*16 | mu 8192*64 | logvar 8192*64]
  float* out_logits = (float*)d_out;
  float* out_mu     = (float*)d_out + 131072;
  float* out_lv     = (float*)d_out + 655360;

  (void)hipMemsetAsync(dmx, 0, 16, stream);
  detect3<<<1, 256, 0, stream>>>((const u16*)d_in[ix], mode);
  detect_adj<<<1, 256, 0, stream>>>((const unsigned*)adj, amode);

  // layer 1: Wh1 = x @ W1 (fp32), s/d, flash (full-row, grid 256), h fp32
  gemm_f32<<<dim3(4, 128), 256, 0, stream>>>(d_in[ix], d_in[iW1], wh1, 512, 256, mode, 1, 1);
  sd_f32<<<2048, 256, 0, stream>>>(wh1, d_in[ia1], s1, d1, dmx + 0, 256, mode);
  flash_f32<256, 32, 4, 1, true><<<256, 256, 0, stream>>>(wh1, s1, d1, dmx + 0, adj, amode, h, nullptr);

  // layers 2/3: whmu/whlv = h @ W, s/d, flash (J-split 4), combine
  gemm_f32<<<dim3(1, 128), 256, 0, stream>>>(h, d_in[iWmu], whmu, 256, 64, mode, 0, 1);
  gemm_f32<<<dim3(1, 128), 256, 0, stream>>>(h, d_in[iWlv], whlv, 256, 64, mode, 0, 1);
  sd_f32<<<2048, 256, 0, stream>>>(whmu, d_in[iamu], smu, dmu, dmx + 1, 64, mode);
  sd_f32<<<2048, 256, 0, stream>>>(whlv, d_in[ialv], slv, dlv, dmx + 2, 64, mode);

  flash_f32<64, 64, 2, 4, false><<<512, 256, 0, stream>>>(whmu, smu, dmu, dmx + 1, adj, amode, parts, lps);
  combine4<<<2048, 256, 0, stream>>>(parts, lps, muf, out_mu);
  flash_f32<64, 64, 2, 4, false><<<512, 256, 0, stream>>>(whlv, slv, dlv, dmx + 2, adj, amode, parts, lps);
  combine4<<<2048, 256, 0, stream>>>(parts, lps, lvf, out_lv);

  logits_f32<<<128, 256, 0, stream>>>(muf, lvf, d_in[ieps], d_in[iWc], d_in[ibc], out_logits, mode);
}

// Round 9
// 2065.804 us; speedup vs baseline: 1.2645x; 1.2645x over previous
//
#include <hip/hip_runtime.h>

typedef unsigned short u16;

#define NROW 8192

__device__ __forceinline__ float bf2f(u16 h) {
  unsigned u = ((unsigned)h) << 16;
  return __builtin_bit_cast(float, u);
}
// mode-aware load: f32 ? fp32 storage : bf16 storage (upcast)
__device__ __forceinline__ float ldf(const void* p, size_t i, int f32) {
  return f32 ? ((const float*)p)[i] : bf2f(((const u16*)p)[i]);
}
// order-preserving float->uint key for atomicMax
__device__ __forceinline__ unsigned fkey(float f) {
  unsigned b = __builtin_bit_cast(unsigned, f);
  return (b & 0x80000000u) ? ~b : (b | 0x80000000u);
}
__device__ __forceinline__ float fkeydec(unsigned k) {
  unsigned b = (k & 0x80000000u) ? (k & 0x7FFFFFFFu) : ~k;
  return __builtin_bit_cast(float, b);
}

// ---- storage-dtype detection on x (N(0,1)).
__global__ void detect3(const u16* __restrict__ xr, unsigned* __restrict__ mode) {
  __shared__ int zc, bg;
  int t = threadIdx.x;   // 256
  if (t == 0) { zc = 0; bg = 0; }
  __syncthreads();
  int zeros_even = 0; int big = 0;
  for (int i = t; i < 4096; i += 256) {
    u16 v = xr[i];
    if (!(i & 1) && v == 0) zeros_even++;
    if (fabsf(bf2f(v)) > 1e6f) big = 1;
  }
  atomicAdd(&zc, zeros_even);
  if (big) atomicOr(&bg, 1);
  __syncthreads();
  if (t == 0) *mode = (zc > 512 || bg) ? 1u : 0u;   // 1 = fp32 storage
}

// ---- adj storage detection (u32 pair pattern 0x00003F80 unique to bf16).
__global__ void detect_adj(const unsigned* __restrict__ a, unsigned* __restrict__ amode) {
  __shared__ int clo;
  int t = threadIdx.x;   // 256
  if (t == 0) clo = 0;
  __syncthreads();
  int c = 0;
  for (int i = t; i < 4096; i += 256)
    if (a[i] == 0x00003F80u) c++;
  atomicAdd(&clo, c);
  __syncthreads();
  if (t == 0) *amode = (clo > 32) ? 1u : 0u;   // 1 = bf16 storage
}

// 4 adjacency bits at element offset base (base % 4 == 0).
__device__ __forceinline__ void mask4(const void* adj, size_t base, int amode, int* aa) {
  if (amode == 0) {   // int32 or fp32 storage: one u32 per element, !=0 test
    int4 av = *(const int4*)((const int*)adj + base);
    aa[0] = av.x != 0; aa[1] = av.y != 0; aa[2] = av.z != 0; aa[3] = av.w != 0;
  } else {            // bf16 storage: one u16 per element
    ushort4 av = *(const ushort4*)((const u16*)adj + base);
    aa[0] = av.x != 0; aa[1] = av.y != 0; aa[2] = av.z != 0; aa[3] = av.w != 0;
  }
}

// C[M x N] fp32 = A[M x K] @ B[K x N]; A/B raw (mode-aware) or fp32 ws buffers.
__global__ __launch_bounds__(256) void gemm_f32(const void* __restrict__ A,
    const void* __restrict__ B, float* __restrict__ C, int K, int N,
    const unsigned* __restrict__ modep, int araw, int braw) {
  int f32a = araw ? (int)*modep : 1;
  int f32b = braw ? (int)*modep : 1;
  __shared__ float sA[16][68];
  __shared__ float sB[16][68];
  int tid = threadIdx.x;
  int rb = blockIdx.y, cb = blockIdx.x;
  int tx = tid & 15, ty = tid >> 4;
  float acc[4][4] = {};
  for (int kt = 0; kt < K; kt += 16) {
    __syncthreads();
#pragma unroll
    for (int it = 0; it < 4; ++it) {
      int idx = tid + it * 256;          // 0..1023
      int m = idx & 63, kk = idx >> 6;
      sA[kk][m] = ldf(A, (size_t)(rb * 64 + m) * K + kt + kk, f32a);
      sB[kk][m] = ldf(B, (size_t)(kt + kk) * N + cb * 64 + m, f32b);
    }
    __syncthreads();
#pragma unroll
    for (int k = 0; k < 16; ++k) {
      float4 av = *(const float4*)&sA[k][ty * 4];
      float4 bv = *(const float4*)&sB[k][tx * 4];
      float aa[4] = {av.x, av.y, av.z, av.w};
      float bb[4] = {bv.x, bv.y, bv.z, bv.w};
#pragma unroll
      for (int r = 0; r < 4; ++r)
#pragma unroll
        for (int c = 0; c < 4; ++c) acc[r][c] += aa[r] * bb[c];
    }
  }
#pragma unroll
  for (int r = 0; r < 4; ++r)
#pragma unroll
    for (int c = 0; c < 4; ++c)
      C[(size_t)(rb * 64 + ty * 4 + r) * N + cb * 64 + tx * 4 + c] = acc[r][c];
}

// s_i = Wh_i . a[:F], d_i = Wh_i . a[F:] (Wh fp32, a raw), + global Dmax.
__global__ __launch_bounds__(256) void sd_f32(const float* __restrict__ Wh,
    const void* __restrict__ a2, float* __restrict__ s, float* __restrict__ d,
    unsigned* __restrict__ cell, int F, const unsigned* __restrict__ modep) {
  int f32 = (int)*modep;
  int row = blockIdx.x * 4 + (threadIdx.x >> 6);
  int l = threadIdx.x & 63;
  float ss = 0.f, dd = 0.f;
  for (int k = l; k < F; k += 64) {
    float wv = Wh[(size_t)row * F + k];
    ss += wv * ldf(a2, k, f32);
    dd += wv * ldf(a2, F + k, f32);
  }
#pragma unroll
  for (int off = 32; off > 0; off >>= 1) {
    ss += __shfl_down(ss, off, 64);
    dd += __shfl_down(dd, off, 64);
  }
  if (l == 0) {
    s[row] = ss; d[row] = dd;
    atomicMax(cell, fkey(dd));
  }
}

// Flash GAT layer, J-split with global fp32 atomic accumulation.
// grid = (8192/R) * JS. Each block: rows [r0, r0+R), j in [js*JLEN, +JLEN).
// Accumulates UNNORMALIZED row sums into acc_g[row*FDIM+f] and lsum_g[row]
// via atomicAdd (both must be zeroed before launch).
template <int FDIM, int R, int RPG, int JS>
__global__ __launch_bounds__(256) void flash_acc(const float* __restrict__ Wh,
    const float* __restrict__ s, const float* __restrict__ d,
    const unsigned* __restrict__ cell, const void* __restrict__ adj,
    const unsigned* __restrict__ amodep,
    float* __restrict__ acc_g, float* __restrict__ lsum_g) {
  constexpr int PST = R + 4;            // Pt j-row stride (floats)
  constexpr int NFG = FDIM / 8;         // feature groups
  constexpr int NRG = 256 / NFG;        // row groups
  static_assert(NRG * RPG == R, "thread geometry");
  static_assert(RPG == 2 || RPG == 4, "RPG path");
  constexpr int UPT = (R * 8) / 256;    // score-phase slots per thread
  constexpr int JLEN = NROW / JS;
  __shared__ __align__(16) float wt[32 * FDIM];
  __shared__ __align__(16) float Pt[32 * PST];
  __shared__ float sd_[R], Ms_[R], dd_[32];
  int tid = threadIdx.x;
  int amode = (int)*amodep;
  int rblk = blockIdx.x / JS;
  int js   = blockIdx.x - rblk * JS;
  int r0 = rblk * R;
  int jbase = js * JLEN;
  int fg = tid % NFG, rg = tid / NFG;
  float Dmax = fkeydec(*cell);
  for (int i = tid; i < R; i += 256) {
    float sv = s[r0 + i];
    sd_[i] = sv;
    float t = sv + Dmax;
    Ms_[i] = fmaxf(t, 0.2f * t);        // lrelu(s_i + Dmax) >= all e[i,:]
  }
  float acc[RPG][8] = {};
  float psum[UPT] = {};
  for (int j0 = jbase; j0 < jbase + JLEN; j0 += 32) {
    __syncthreads();                    // prior readers of wt/Pt/dd_ done
    if (tid < 32) dd_[tid] = d[j0 + tid];
    for (int u = tid; u < 32 * FDIM / 4; u += 256)
      *(float4*)&wt[u * 4] = *(const float4*)&Wh[(size_t)j0 * FDIM + u * 4];
    __syncthreads();                    // wt/dd_ ready
#pragma unroll
    for (int up = 0; up < UPT; ++up) {
      int u = tid + up * 256;
      int r = u >> 3, jq = (u & 7) * 4;
      int aa[4];
      mask4(adj, (size_t)(r0 + r) * NROW + j0 + jq, amode, aa);
      float sv = sd_[r], Mr = Ms_[r];
#pragma unroll
      for (int i2 = 0; i2 < 4; ++i2) {
        float t = sv + dd_[jq + i2];
        float e = fmaxf(t, 0.2f * t) - Mr;       // <= 0
        float p = aa[i2] ? __expf(e) : 0.f;
        psum[up] += p;
        Pt[(jq + i2) * PST + r] = p;             // j-major
      }
    }
    __syncthreads();                    // Pt complete
#pragma unroll 4
    for (int j = 0; j < 32; ++j) {
      float4 w0 = *(const float4*)&wt[j * FDIM + fg * 8];
      float4 w1 = *(const float4*)&wt[j * FDIM + fg * 8 + 4];
      float wv[8] = {w0.x, w0.y, w0.z, w0.w, w1.x, w1.y, w1.z, w1.w};
      float pv[RPG];
      if constexpr (RPG == 4) {
        float4 p0 = *(const float4*)&Pt[j * PST + rg * 4];
        pv[0] = p0.x; pv[1] = p0.y; pv[2] = p0.z; pv[3] = p0.w;
      } else {   // RPG == 2
        float2 p0 = *(const float2*)&Pt[j * PST + rg * 2];
        pv[0] = p0.x; pv[1] = p0.y;
      }
#pragma unroll
      for (int rr = 0; rr < RPG; ++rr)
#pragma unroll
        for (int b = 0; b < 8; ++b) acc[rr][b] += pv[rr] * wv[b];
    }
  }
  // ---- lsum: per-thread psum -> LDS (reuse Pt) -> one atomic per row
  __syncthreads();
#pragma unroll
  for (int up = 0; up < UPT; ++up) {
    int u = tid + up * 256;
    Pt[u] = psum[up];                   // Pt[r*8 + c]
  }
  __syncthreads();
  if (tid < R) {
    float t = 0.f;
#pragma unroll
    for (int c = 0; c < 8; ++c) t += Pt[tid * 8 + c];
    atomicAdd(&lsum_g[r0 + tid], t);
  }
  // ---- accumulator flush (scattered, conflict-free addresses)
#pragma unroll
  for (int rr = 0; rr < RPG; ++rr) {
    int rl = rg * RPG + rr;
#pragma unroll
    for (int b = 0; b < 8; ++b)
      atomicAdd(&acc_g[(size_t)(r0 + rl) * FDIM + fg * 8 + b], acc[rr][b]);
  }
}

// h = elu(acc/lsum) fp32 (layer 1). n = 8192*256.
__global__ __launch_bounds__(256) void combine_elu(const float* __restrict__ acc_g,
    const float* __restrict__ lsum_g, float* __restrict__ h) {
  int idx = blockIdx.x * 256 + threadIdx.x;
  float x = acc_g[idx] / lsum_g[idx >> 8];
  h[idx] = (x > 0.f) ? x : (__expf(x) - 1.f);
}

// out = acc/lsum fp32, dual store (ws buffer + d_out region). n = 8192*64.
__global__ __launch_bounds__(256) void combine_div(const float* __restrict__ acc_g,
    const float* __restrict__ lsum_g, float* __restrict__ outf, float* __restrict__ outd) {
  int idx = blockIdx.x * 256 + threadIdx.x;
  float x = acc_g[idx] / lsum_g[idx >> 6];
  outf[idx] = x;
  outd[idx] = x;
}

// logits = (mu + eps*exp(0.5*logvar)) @ Wc + bc (mu/lv fp32, rest raw). fp32 out.
__global__ __launch_bounds__(256) void logits_f32(const float* __restrict__ mu,
    const float* __restrict__ lv, const void* __restrict__ eps,
    const void* __restrict__ Wc, const void* __restrict__ bcv,
    float* __restrict__ outL, const unsigned* __restrict__ modep) {
  int f32 = (int)*modep;
  __shared__ float zs[64 * 64];
  __shared__ float wcs[64 * 16];
  int tid = threadIdx.x;
  for (int i = tid; i < 1024; i += 256) wcs[i] = ldf(Wc, i, f32);
  int rl = tid >> 2, cs = (tid & 3) * 16;
  int row = blockIdx.x * 64 + rl;
  size_t rb64 = (size_t)row * 64;
  for (int c = cs; c < cs + 16; ++c)
    zs[rl * 64 + c] = mu[rb64 + c] + ldf(eps, rb64 + c, f32) * __expf(0.5f * lv[rb64 + c]);
  __syncthreads();
  for (int it = tid; it < 1024; it += 256) {
    int r = it >> 4, oc = it & 15;
    float a = ldf(bcv, oc, f32);
    for (int c = 0; c < 64; ++c) a += zs[r * 64 + c] * wcs[c * 16 + oc];
    outL[(size_t)(blockIdx.x * 64 + r) * 16 + oc] = a;
  }
}

extern "C" void kernel_launch(void* const* d_in, const int* in_sizes, int n_in,
                              void* d_out, int out_size, void* d_ws, size_t ws_size,
                              hipStream_t stream) {
  (void)out_size; (void)ws_size;
  // ---- size-based input resolution (robust to permutation; ties in dict order)
  int ix = 0, iadj = 1, ieps = 2, iW1 = 3, ia1 = 4, iWmu = 5, iamu = 6,
      iWlv = 7, ialv = 8, iWc = 9, ibc = 10;
  {
    int fmu = -1, flv = -1, fam = -1, fal = -1;
    for (int i = 0; i < n_in; ++i) {
      switch (in_sizes[i]) {
        case 67108864: iadj = i; break;
        case 4194304:  ix   = i; break;
        case 524288:   ieps = i; break;
        case 131072:   iW1  = i; break;
        case 512:      ia1  = i; break;
        case 1024:     iWc  = i; break;
        case 16:       ibc  = i; break;
        case 16384:    if (fmu < 0) fmu = i; else flv = i; break;
        case 128:      if (fam < 0) fam = i; else fal = i; break;
        default: break;
      }
    }
    if (fmu >= 0 && flv >= 0) { iWmu = fmu; iWlv = flv; }
    if (fam >= 0 && fal >= 0) { iamu = fam; ialv = fal; }
  }
  const void* adj = d_in[iadj];
  char* ws = (char*)d_ws;
  const size_t KB = 1024, MB = 1024 * 1024;
  // ---- workspace (<= 24.6 MB) ----
  float* wh1   = (float*)(ws + 0);                 // 8MB [dead after flash1]
  float* whmu  = (float*)(ws + 0);                 // 2MB [overlay]
  float* whlv  = (float*)(ws + 2 * MB);            // 2MB [overlay]
  float* muf   = (float*)(ws + 4 * MB);            // 2MB [overlay]
  float* lvf   = (float*)(ws + 6 * MB);            // 2MB [overlay]
  float* h     = (float*)(ws + 8 * MB);            // 8MB
  float* hacc  = (float*)(ws + 16 * MB);           // 8MB [dead after combine1]
  float* macc  = (float*)(ws + 16 * MB);           // 2MB [overlay, memset mid-stream]
  float* lvacc = (float*)(ws + 18 * MB);           // 2MB [overlay, memset mid-stream]
  float* lsum1 = (float*)(ws + 24 * MB);           // 32KB
  float* lsmu  = (float*)(ws + 24 * MB + 32 * KB);
  float* lslv  = (float*)(ws + 24 * MB + 64 * KB);
  float* s1    = (float*)(ws + 24 * MB + 96 * KB);
  float* d1    = (float*)(ws + 24 * MB + 128 * KB);
  float* smu   = (float*)(ws + 24 * MB + 160 * KB);
  float* dmu   = (float*)(ws + 24 * MB + 192 * KB);
  float* slv   = (float*)(ws + 24 * MB + 224 * KB);
  float* dlv   = (float*)(ws + 24 * MB + 256 * KB);
  unsigned* dmx   = (unsigned*)(ws + 24 * MB + 288 * KB);  // 4 cells
  unsigned* mode  = (unsigned*)(ws + 24 * MB + 289 * KB);
  unsigned* amode = (unsigned*)(ws + 24 * MB + 290 * KB);

  // fp32 output layout: [logits 8192*16 | mu 8192*64 | logvar 8192*64]
  float* out_logits = (float*)d_out;
  float* out_mu     = (float*)d_out + 131072;
  float* out_lv     = (float*)d_out + 655360;

  (void)hipMemsetAsync(dmx, 0, 16, stream);
  (void)hipMemsetAsync(lsum1, 0, 96 * KB, stream);        // lsum1+lsmu+lslv
  (void)hipMemsetAsync(hacc, 0, 8 * MB, stream);
  detect3<<<1, 256, 0, stream>>>((const u16*)d_in[ix], mode);
  detect_adj<<<1, 256, 0, stream>>>((const unsigned*)adj, amode);

  // layer 1: Wh1 = x @ W1 (fp32), s/d, flash (JS=4, 4 blocks/CU), combine+elu
  gemm_f32<<<dim3(4, 128), 256, 0, stream>>>(d_in[ix], d_in[iW1], wh1, 512, 256, mode, 1, 1);
  sd_f32<<<2048, 256, 0, stream>>>(wh1, d_in[ia1], s1, d1, dmx + 0, 256, mode);
  flash_acc<256, 32, 4, 4><<<1024, 256, 0, stream>>>(wh1, s1, d1, dmx + 0, adj, amode, hacc, lsum1);
  combine_elu<<<8192, 256, 0, stream>>>(hacc, lsum1, h);

  // zero layer-2/3 accumulators (overlaying dead hacc; stream-ordered)
  (void)hipMemsetAsync(macc, 0, 4 * MB, stream);          // macc + lvacc

  // layers 2/3: whmu/whlv = h @ W, s/d, flash (JS=16, 8 blocks/CU), combine
  gemm_f32<<<dim3(1, 128), 256, 0, stream>>>(h, d_in[iWmu], whmu, 256, 64, mode, 0, 1);
  gemm_f32<<<dim3(1, 128), 256, 0, stream>>>(h, d_in[iWlv], whlv, 256, 64, mode, 0, 1);
  sd_f32<<<2048, 256, 0, stream>>>(whmu, d_in[iamu], smu, dmu, dmx + 1, 64, mode);
  sd_f32<<<2048, 256, 0, stream>>>(whlv, d_in[ialv], slv, dlv, dmx + 2, 64, mode);
  flash_acc<64, 64, 2, 16><<<2048, 256, 0, stream>>>(whmu, smu, dmu, dmx + 1, adj, amode, macc, lsmu);
  flash_acc<64, 64, 2, 16><<<2048, 256, 0, stream>>>(whlv, slv, dlv, dmx + 2, adj, amode, lvacc, lslv);
  combine_div<<<2048, 256, 0, stream>>>(macc, lsmu, muf, out_mu);
  combine_div<<<2048, 256, 0, stream>>>(lvacc, lslv, lvf, out_lv);

  logits_f32<<<128, 256, 0, stream>>>(muf, lvf, d_in[ieps], d_in[iWc], d_in[ibc], out_logits, mode);
}